// Round 4
// baseline (281.270 us; speedup 1.0000x reference)
//
#include <hip/hip_runtime.h>
#include <hip/hip_bf16.h>

#define K_CLS 20
#define HIN 480
#define WIN 640
#define NPIX (HIN * WIN)
#define C_ 512
#define H_ 30
#define W_ 40
#define NB_ 5
#define CNT_THRESH 10000
// out layout (fp32): pool_x[2048], NB, N, x_cropped[6*4*512*30*40]
#define XCROP_ELEMS (6 * 4 * C_ * H_ * W_)
#define OUT_TOTAL (2050 + XCROP_ELEMS)
#define NPAIR (OUT_TOTAL / 2)          // 7,373,825 (OUT_TOTAL is even)

#define NBLK_STATS 300                 // NPIX/4/256 exactly
#define NODE_OFF (NBLK_STATS * 100)    // ws int offset of the 5 node boxes

// ws int layout: [block][cnt20|mnx20|mny20|mxx20|mxy20] * 300, then boxes[5*4]

__global__ void stats_k(const float* __restrict__ seg, int* __restrict__ ws) {
    __shared__ int s_cnt[K_CLS], s_mnx[K_CLS], s_mny[K_CLS], s_mxx[K_CLS], s_mxy[K_CLS];
    int t = threadIdx.x;
    if (t < K_CLS) { s_cnt[t] = 0; s_mnx[t] = WIN; s_mny[t] = HIN; s_mxx[t] = -1; s_mxy[t] = -1; }
    __syncthreads();

    int p = blockIdx.x * blockDim.x + t;                 // quad-pixel index, 0..76799
    const float4* base = (const float4*)(seg + (size_t)3 * K_CLS * NPIX) + p;
    float4 v = base[0];
    float b0 = v.x, b1 = v.y, b2 = v.z, b3 = v.w;
    int k0 = 0, k1 = 0, k2 = 0, k3 = 0;
    #pragma unroll
    for (int k = 1; k < K_CLS; k++) {                    // strict > : np.argmax tie-break
        float4 u = base[(size_t)k * (NPIX / 4)];
        if (u.x > b0) { b0 = u.x; k0 = k; }
        if (u.y > b1) { b1 = u.y; k1 = k; }
        if (u.z > b2) { b2 = u.z; k2 = k; }
        if (u.w > b3) { b3 = u.w; k3 = k; }
    }
    int x = (p * 4) % WIN, y = (p * 4) / WIN;            // quad never wraps a row (640%4==0)
    if (k0 == k1 && k1 == k2 && k2 == k3) {              // common case: uniform class
        atomicAdd(&s_cnt[k0], 4);
        atomicMin(&s_mnx[k0], x);     atomicMax(&s_mxx[k0], x + 3);
        atomicMin(&s_mny[k0], y);     atomicMax(&s_mxy[k0], y);
    } else {
        int ks[4] = {k0, k1, k2, k3};
        #pragma unroll
        for (int i = 0; i < 4; i++) {
            atomicAdd(&s_cnt[ks[i]], 1);
            atomicMin(&s_mnx[ks[i]], x + i);  atomicMax(&s_mxx[ks[i]], x + i);
            atomicMin(&s_mny[ks[i]], y);      atomicMax(&s_mxy[ks[i]], y);
        }
    }
    __syncthreads();
    if (t < 100) {                                       // per-block partial, plain store
        int a = t / 20, c = t % 20;
        int val = (a == 0) ? s_cnt[c] : (a == 1) ? s_mnx[c] : (a == 2) ? s_mny[c]
                : (a == 3) ? s_mxx[c] : s_mxy[c];
        ws[blockIdx.x * 100 + t] = val;
    }
}

__global__ void plan_k(int* __restrict__ ws) {
    __shared__ int st[100];
    int t = threadIdx.x;
    if (t < 100) {
        int a = t / 20;
        int acc = (a == 0) ? 0 : (a == 1) ? WIN : (a == 2) ? HIN : -1;
        for (int b = 0; b < NBLK_STATS; b++) {
            int v = ws[b * 100 + t];
            if (a == 0)      acc += v;
            else if (a <= 2) acc = v < acc ? v : acc;
            else             acc = v > acc ? v : acc;
        }
        st[t] = acc;
    }
    __syncthreads();
    if (t != 0) return;

    int* cnt = st;
    int* mnx = st + 20; int* mny = st + 40; int* mxx = st + 60; int* mxy = st + 80;
    int* nb  = ws + NODE_OFF;

    // np.unique -> sorted present ids; drop smallest present id
    int firstp = -1;
    for (int i = 0; i < K_CLS; i++) if (cnt[i] > 0) { firstp = i; break; }
    int order[K_CLS]; int nc = 0;
    for (int i = 0; i < K_CLS; i++)
        if (cnt[i] > 0 && i != firstp) order[nc++] = i;

    // stable insertion sort, descending by count
    for (int i = 1; i < nc; i++) {
        int key = order[i]; int j = i - 1;
        while (j >= 0 && cnt[order[j]] < cnt[key]) { order[j + 1] = order[j]; j--; }
        order[j + 1] = key;
    }

    int nsel = 0;
    for (int i = 0; i < nc && nsel < NB_ - 2; i++) {
        int b = order[i];
        if (cnt[b] > CNT_THRESH) {
            nb[nsel * 4 + 0] = mnx[b] >> 4;
            nb[nsel * 4 + 1] = mny[b] >> 4;
            nb[nsel * 4 + 2] = mxx[b] >> 4;
            nb[nsel * 4 + 3] = mxy[b] >> 4;
            nsel++;
        }
    }
    const int bb[5][4] = {
        {W_ / 4, H_ / 4, 3 * W_ / 4, 3 * H_ / 4},
        {0, 0, W_ / 3, H_},
        {0, 0, W_, H_ / 3},
        {2 * W_ / 3, 0, W_, H_},
        {0, 2 * H_ / 3, W_, H_}
    };
    for (int i = 0; nsel < NB_; i++, nsel++) {
        nb[nsel * 4 + 0] = bb[i][0];
        nb[nsel * 4 + 1] = bb[i][1];
        nb[nsel * 4 + 2] = bb[i][2];
        nb[nsel * 4 + 3] = bb[i][3];
    }
}

__global__ void out_k(const float* __restrict__ feat,
                      const float* __restrict__ pool_x,
                      const int* __restrict__ nb,
                      float* __restrict__ out) {
    int e = blockIdx.x * blockDim.x + threadIdx.x;       // pair index
    if (e >= NPAIR) return;
    int i0 = e * 2;
    float2* o = (float2*)out + e;
    if (i0 < 2048) { *o = ((const float2*)pool_x)[e]; return; }
    if (i0 == 2048) { *o = make_float2(5.0f, 4.0f); return; }   // NB, N

    int j  = i0 - 2050;          // even; pair shares sn,c,h and w,w+1 (W=40 even)
    int w  = j % W_;
    int t1 = j / W_;
    int h  = t1 % H_;
    int t2 = t1 / H_;
    int c  = t2 & (C_ - 1);
    int sn = t2 >> 9;            // (s*4+n), 0..23

    if (sn >= 20) {              // s == 5 -> raw feat copy
        int n = sn - 20;
        *o = *(const float2*)(feat + (((size_t)(n * C_ + c) * H_ + h) * W_ + w));
        return;
    }
    int b  = sn % NB_;           // reshape (4,5,..)->(5,4,..)
    int n2 = sn / NB_;
    int x0 = nb[b * 4 + 0], y0 = nb[b * 4 + 1];
    int x1 = nb[b * 4 + 2], y1 = nb[b * 4 + 3];
    int iw = x1 - x0; if (iw < 1) iw = 1;
    int ih = y1 - y0; if (ih < 1) ih = 1;

    const float* src = feat + (size_t)(n2 * C_ + c) * H_ * W_;

    // half-pixel-center bilinear; scale>=1 so antialias inert, edge renorm == clamp
    float fy  = (h + 0.5f) * (float)ih / (float)H_ - 0.5f;
    float flY = floorf(fy);
    float ty  = fy - flY;
    int ylo = (int)flY, yhi = ylo + 1;
    ylo = min(max(ylo, 0), ih - 1);
    yhi = min(max(yhi, 0), ih - 1);
    int r0 = (y0 + ylo) * W_, r1 = (y0 + yhi) * W_;

    float res[2];
    #pragma unroll
    for (int i = 0; i < 2; i++) {
        float fx  = (w + i + 0.5f) * (float)iw / (float)W_ - 0.5f;
        float flX = floorf(fx);
        float tx  = fx - flX;
        int xlo = (int)flX, xhi = xlo + 1;
        xlo = min(max(xlo, 0), iw - 1);
        xhi = min(max(xhi, 0), iw - 1);
        float v00 = src[r0 + x0 + xlo], v01 = src[r0 + x0 + xhi];
        float v10 = src[r1 + x0 + xlo], v11 = src[r1 + x0 + xhi];
        res[i] = (1.0f - ty) * ((1.0f - tx) * v00 + tx * v01)
               +         ty  * ((1.0f - tx) * v10 + tx * v11);
    }
    *o = make_float2(res[0], res[1]);
}

extern "C" void kernel_launch(void* const* d_in, const int* in_sizes, int n_in,
                              void* d_out, int out_size, void* d_ws, size_t ws_size,
                              hipStream_t stream) {
    const float* seg    = (const float*)d_in[0];
    const float* feat   = (const float*)d_in[1];
    const float* pool_x = (const float*)d_in[2];
    float* out = (float*)d_out;
    int* ws = (int*)d_ws;

    stats_k<<<NBLK_STATS, 256, 0, stream>>>(seg, ws);
    plan_k<<<1, 128, 0, stream>>>(ws);
    out_k<<<(NPAIR + 255) / 256, 256, 0, stream>>>(feat, pool_x, ws + NODE_OFF, out);
}

// Round 5
// 216.244 us; speedup vs baseline: 1.3007x; 1.3007x over previous
//
#include <hip/hip_runtime.h>
#include <hip/hip_bf16.h>

#define K_CLS 20
#define HIN 480
#define WIN 640
#define NPIX (HIN * WIN)
#define C_ 512
#define H_ 30
#define W_ 40
#define NB_ 5
#define CNT_THRESH 10000
// out layout (fp32): pool_x[2048], NB, N, x_cropped[6*4*512*30*40]
#define XCROP_ELEMS (6 * 4 * C_ * H_ * W_)
#define OUT_TOTAL (2050 + XCROP_ELEMS)
#define NPAIR (OUT_TOTAL / 2)          // OUT_TOTAL is even

#define NBLK_STATS 300                 // NPIX/4/256 exactly
#define NODE_OFF (NBLK_STATS * 100)    // ws int offset of the 5 node boxes

// ws int layout: [block][cnt20|mnx20|mny20|mxx20|mxy20] * 300, then boxes[5*4]

__global__ void stats_k(const float* __restrict__ seg, int* __restrict__ ws) {
    __shared__ int s_cnt[K_CLS], s_mnx[K_CLS], s_mny[K_CLS], s_mxx[K_CLS], s_mxy[K_CLS];
    int t = threadIdx.x;
    if (t < K_CLS) { s_cnt[t] = 0; s_mnx[t] = WIN; s_mny[t] = HIN; s_mxx[t] = -1; s_mxy[t] = -1; }
    __syncthreads();

    int p = blockIdx.x * blockDim.x + t;                 // quad-pixel index, 0..76799
    const float4* base = (const float4*)(seg + (size_t)3 * K_CLS * NPIX) + p;
    float4 v = base[0];
    float b0 = v.x, b1 = v.y, b2 = v.z, b3 = v.w;
    int k0 = 0, k1 = 0, k2 = 0, k3 = 0;
    #pragma unroll
    for (int k = 1; k < K_CLS; k++) {                    // strict > : np.argmax tie-break
        float4 u = base[(size_t)k * (NPIX / 4)];
        if (u.x > b0) { b0 = u.x; k0 = k; }
        if (u.y > b1) { b1 = u.y; k1 = k; }
        if (u.z > b2) { b2 = u.z; k2 = k; }
        if (u.w > b3) { b3 = u.w; k3 = k; }
    }
    int x = (p * 4) % WIN, y = (p * 4) / WIN;            // quad never wraps a row (640%4==0)
    if (k0 == k1 && k1 == k2 && k2 == k3) {              // common case: uniform class
        atomicAdd(&s_cnt[k0], 4);
        atomicMin(&s_mnx[k0], x);     atomicMax(&s_mxx[k0], x + 3);
        atomicMin(&s_mny[k0], y);     atomicMax(&s_mxy[k0], y);
    } else {
        int ks[4] = {k0, k1, k2, k3};
        #pragma unroll
        for (int i = 0; i < 4; i++) {
            atomicAdd(&s_cnt[ks[i]], 1);
            atomicMin(&s_mnx[ks[i]], x + i);  atomicMax(&s_mxx[ks[i]], x + i);
            atomicMin(&s_mny[ks[i]], y);      atomicMax(&s_mxy[ks[i]], y);
        }
    }
    __syncthreads();
    if (t < 100) {                                       // per-block partial, plain store
        int a = t / 20, c = t % 20;
        int val = (a == 0) ? s_cnt[c] : (a == 1) ? s_mnx[c] : (a == 2) ? s_mny[c]
                : (a == 3) ? s_mxx[c] : s_mxy[c];
        ws[blockIdx.x * 100 + t] = val;
    }
}

// Parallel reduce 300 partial records -> final stats -> boxes.
// R4 post-mortem: the previous serial version (100 threads x 300 strided
// loads, 1 block) was 100 us, the hottest kernel on the device. This one
// spreads the 30k loads over 1000 threads (10 chunks x 100 cols, coalesced).
__global__ void plan_k(int* __restrict__ ws) {
    __shared__ int part[10][100];
    __shared__ int st[100];
    int t = threadIdx.x;                 // 0..1023
    if (t < 1000) {
        int c = t % 100, chunk = t / 100;
        int a = c / 20;
        int acc = (a == 0) ? 0 : (a == 1) ? WIN : (a == 2) ? HIN : -1;
        #pragma unroll
        for (int i = 0; i < 30; i++) {
            int v = ws[(chunk * 30 + i) * 100 + c];
            if (a == 0)      acc += v;
            else if (a <= 2) acc = v < acc ? v : acc;
            else             acc = v > acc ? v : acc;
        }
        part[chunk][c] = acc;
    }
    __syncthreads();
    if (t < 100) {
        int a = t / 20;
        int acc = part[0][t];
        #pragma unroll
        for (int i = 1; i < 10; i++) {
            int v = part[i][t];
            if (a == 0)      acc += v;
            else if (a <= 2) acc = v < acc ? v : acc;
            else             acc = v > acc ? v : acc;
        }
        st[t] = acc;
    }
    __syncthreads();
    if (t != 0) return;

    int* cnt = st;
    int* mnx = st + 20; int* mny = st + 40; int* mxx = st + 60; int* mxy = st + 80;
    int* nb  = ws + NODE_OFF;

    // np.unique -> sorted present ids; drop smallest present id
    int firstp = -1;
    for (int i = 0; i < K_CLS; i++) if (cnt[i] > 0) { firstp = i; break; }
    int order[K_CLS]; int nc = 0;
    for (int i = 0; i < K_CLS; i++)
        if (cnt[i] > 0 && i != firstp) order[nc++] = i;

    // stable insertion sort, descending by count
    for (int i = 1; i < nc; i++) {
        int key = order[i]; int j = i - 1;
        while (j >= 0 && cnt[order[j]] < cnt[key]) { order[j + 1] = order[j]; j--; }
        order[j + 1] = key;
    }

    int nsel = 0;
    for (int i = 0; i < nc && nsel < NB_ - 2; i++) {
        int b = order[i];
        if (cnt[b] > CNT_THRESH) {
            nb[nsel * 4 + 0] = mnx[b] >> 4;
            nb[nsel * 4 + 1] = mny[b] >> 4;
            nb[nsel * 4 + 2] = mxx[b] >> 4;
            nb[nsel * 4 + 3] = mxy[b] >> 4;
            nsel++;
        }
    }
    const int bb[5][4] = {
        {W_ / 4, H_ / 4, 3 * W_ / 4, 3 * H_ / 4},
        {0, 0, W_ / 3, H_},
        {0, 0, W_, H_ / 3},
        {2 * W_ / 3, 0, W_, H_},
        {0, 2 * H_ / 3, W_, H_}
    };
    for (int i = 0; nsel < NB_; i++, nsel++) {
        nb[nsel * 4 + 0] = bb[i][0];
        nb[nsel * 4 + 1] = bb[i][1];
        nb[nsel * 4 + 2] = bb[i][2];
        nb[nsel * 4 + 3] = bb[i][3];
    }
}

__global__ void out_k(const float* __restrict__ feat,
                      const float* __restrict__ pool_x,
                      const int* __restrict__ nb,
                      float* __restrict__ out) {
    int e = blockIdx.x * blockDim.x + threadIdx.x;       // pair index
    if (e >= NPAIR) return;
    int i0 = e * 2;
    float2* o = (float2*)out + e;
    if (i0 < 2048) { *o = ((const float2*)pool_x)[e]; return; }
    if (i0 == 2048) { *o = make_float2(5.0f, 4.0f); return; }   // NB, N

    int j  = i0 - 2050;          // even; pair shares sn,c,h and w,w+1 (W=40 even)
    int w  = j % W_;
    int t1 = j / W_;
    int h  = t1 % H_;
    int t2 = t1 / H_;
    int c  = t2 & (C_ - 1);
    int sn = t2 >> 9;            // (s*4+n), 0..23

    if (sn >= 20) {              // s == 5 -> raw feat copy
        int n = sn - 20;
        *o = *(const float2*)(feat + (((size_t)(n * C_ + c) * H_ + h) * W_ + w));
        return;
    }
    int b  = sn % NB_;           // reshape (4,5,..)->(5,4,..)
    int n2 = sn / NB_;
    int x0 = nb[b * 4 + 0], y0 = nb[b * 4 + 1];
    int x1 = nb[b * 4 + 2], y1 = nb[b * 4 + 3];
    int iw = x1 - x0; if (iw < 1) iw = 1;
    int ih = y1 - y0; if (ih < 1) ih = 1;

    const float* src = feat + (size_t)(n2 * C_ + c) * H_ * W_;

    // half-pixel-center bilinear; scale>=1 so antialias inert, edge renorm == clamp
    float fy  = (h + 0.5f) * (float)ih / (float)H_ - 0.5f;
    float flY = floorf(fy);
    float ty  = fy - flY;
    int ylo = (int)flY, yhi = ylo + 1;
    ylo = min(max(ylo, 0), ih - 1);
    yhi = min(max(yhi, 0), ih - 1);
    int r0 = (y0 + ylo) * W_, r1 = (y0 + yhi) * W_;

    float res[2];
    #pragma unroll
    for (int i = 0; i < 2; i++) {
        float fx  = (w + i + 0.5f) * (float)iw / (float)W_ - 0.5f;
        float flX = floorf(fx);
        float tx  = fx - flX;
        int xlo = (int)flX, xhi = xlo + 1;
        xlo = min(max(xlo, 0), iw - 1);
        xhi = min(max(xhi, 0), iw - 1);
        float v00 = src[r0 + x0 + xlo], v01 = src[r0 + x0 + xhi];
        float v10 = src[r1 + x0 + xlo], v11 = src[r1 + x0 + xhi];
        res[i] = (1.0f - ty) * ((1.0f - tx) * v00 + tx * v01)
               +         ty  * ((1.0f - tx) * v10 + tx * v11);
    }
    *o = make_float2(res[0], res[1]);
}

extern "C" void kernel_launch(void* const* d_in, const int* in_sizes, int n_in,
                              void* d_out, int out_size, void* d_ws, size_t ws_size,
                              hipStream_t stream) {
    const float* seg    = (const float*)d_in[0];
    const float* feat   = (const float*)d_in[1];
    const float* pool_x = (const float*)d_in[2];
    float* out = (float*)d_out;
    int* ws = (int*)d_ws;

    stats_k<<<NBLK_STATS, 256, 0, stream>>>(seg, ws);
    plan_k<<<1, 1024, 0, stream>>>(ws);
    out_k<<<(NPAIR + 255) / 256, 256, 0, stream>>>(feat, pool_x, ws + NODE_OFF, out);
}